// Round 10
// baseline (256.460 us; speedup 1.0000x reference)
//
#include <hip/hip_runtime.h>

#define DD 16
#define HH 128
#define WW 128
#define DHW (DD * HH * WW)   // 262144
#define CIN 16
#define COUT 32
#define KK 27
#define NOFF 81
#define NKC 14               // K-chunks of 32 over (tap,ci); taps padded 27->28
#define NNT 6                // phase-1 n-tiles of 16 over 81->96

// padded sample volume: covers every reachable corner (incl. fp16 tanh = +/-1.0)
#define PADX 5
#define PADY 5
#define PADZ 3
#define PWW 139
#define PHH 139
#define PDD 23
#define PZS (PHH * PWW)      // 19321
#define PVOX (PDD * PZS)     // 444,383 voxels

typedef _Float16 h2    __attribute__((ext_vector_type(2)));
typedef _Float16 f16x8 __attribute__((ext_vector_type(8)));
typedef float    f32x4 __attribute__((ext_vector_type(4)));
struct H16 { h2 v[8]; };     // 16 fp16 channels = 32 B

// ---- ws layout ----
// [0, ~13.6MB)  xp  : fp16 zero-padded [PDD][PHH][PWW][16]
// [+84K)        wBf : off_w in MFMA B-frag order [kc][n][lane][8]   (phase 1)
// [+28K)        wW3 : weight in MFMA A-frag order [kc][mo][lane][8] (phase 3)
#define XP_BYTES   ((size_t)PVOX * 32)
#define WBF_OFF    ((XP_BYTES + 255) & ~(size_t)255)
#define WBF_ELEMS  (NKC * NNT * 64 * 8)               // 43008 halves
#define WW3_OFF    (WBF_OFF + (size_t)WBF_ELEMS * 2)
#define WW3_ELEMS  (NKC * 2 * 64 * 8)                 // 14336 halves
#define WS_NEED    (WW3_OFF + (size_t)WW3_ELEMS * 2)

__device__ __forceinline__ float fast_tanh(float s) {
    float e = __expf(fminf(2.f * s, 80.f));
    return (e - 1.f) * __builtin_amdgcn_rcpf(e + 1.f);
}

// x [ci][z][y][x] fp32 -> xp padded [zp][yp][xp][ci] fp16 (zeros outside)
__global__ __launch_bounds__(192) void pad_x_h(const float* __restrict__ x,
                                               H16* __restrict__ xp) {
    const int xpi = threadIdx.x;
    if (xpi >= PWW) return;
    const int zp = blockIdx.x / PHH;
    const int yp = blockIdx.x - zp * PHH;
    const int z = zp - PADZ, y = yp - PADY, xw = xpi - PADX;
    H16 o;
    if ((unsigned)z < (unsigned)DD && (unsigned)y < (unsigned)HH &&
        (unsigned)xw < (unsigned)WW) {
        const int vox = (z * HH + y) * WW + xw;
#pragma unroll
        for (int p = 0; p < 8; ++p) {
            o.v[p][0] = (_Float16)x[(size_t)(2 * p) * DHW + vox];
            o.v[p][1] = (_Float16)x[(size_t)(2 * p + 1) * DHW + vox];
        }
    } else {
#pragma unroll
        for (int p = 0; p < 8; ++p) { o.v[p][0] = (_Float16)0.f; o.v[p][1] = (_Float16)0.f; }
    }
    xp[(size_t)(zp * PHH + yp) * PWW + xpi] = o;
}

// Pack off_w into phase-1 B fragments and weight into phase-3 A fragments.
__global__ __launch_bounds__(256) void pack_w(const float* __restrict__ off_w,
                                              const float* __restrict__ weight,
                                              _Float16* __restrict__ wBf,
                                              _Float16* __restrict__ wW3) {
    int idx = blockIdx.x * 256 + threadIdx.x;
    if (idx < WBF_ELEMS) {
        int i    = idx & 7;
        int lane = (idx >> 3) & 63;
        int fn   = idx >> 9;            // kc*NNT + n
        int n    = fn % NNT;
        int kc   = fn / NNT;
        int g    = lane >> 4;
        int t    = kc * 2 + (g >> 1);
        int ci   = (g & 1) * 8 + i;
        int j    = n * 16 + (lane & 15);
        float v = 0.f;
        if (t < KK && j < NOFF) v = off_w[(size_t)(j * CIN + ci) * KK + t];
        wBf[idx] = (_Float16)v;
    }
    if (idx < WW3_ELEMS) {
        int i    = idx & 7;
        int lane = (idx >> 3) & 63;
        int fm   = idx >> 9;            // kc*2 + mo
        int mo   = fm & 1;
        int kc   = fm >> 1;
        int g    = lane >> 4;
        int t    = kc * 2 + (g >> 1);
        int ci   = (g & 1) * 8 + i;
        int o    = mo * 16 + (lane & 15);
        float v = 0.f;
        if (t < KK) v = weight[(size_t)(o * CIN + ci) * KK + t];
        wW3[idx] = (_Float16)v;
    }
}

// ---------------------------------------------------------------------------
// Fused kernel (R5 structure) on the zero-padded volume: no validity logic,
// no clamps; corner addresses = base + compile-time-constant offsets.
// ---------------------------------------------------------------------------
__global__ __launch_bounds__(128, 3) void deform_full(
    const f16x8* __restrict__ xp16,   // 2 per padded voxel (8 ch each)
    const f16x8* __restrict__ wBf,    // phase-1 B fragments
    const f16x8* __restrict__ wW3,    // phase-3 A fragments
    const float* __restrict__ off_b,  // [81]
    const float* __restrict__ bias,   // [32]
    float* __restrict__ out)          // [32][DHW]
{
    // offsets: [local w][tap*3+comp] fp16, row stride 84 halves (168B)
    __shared__ _Float16 loff[128 * 84];

    const int lb = ((blockIdx.x & 7) << 8) | (blockIdx.x >> 3);  // XCD swizzle
    const int h = lb & (HH - 1);
    const int d = lb >> 7;
    const int lane = threadIdx.x & 63;
    const int wave = threadIdx.x >> 6;
    const int g = lane >> 4;
    const int col = lane & 15;

    // ---- phase 1: offset conv as implicit GEMM (reads padded volume) ----
    f32x4 acc[4][NNT];
#pragma unroll
    for (int mi = 0; mi < 4; ++mi)
#pragma unroll
        for (int n = 0; n < NNT; ++n) acc[mi][n] = f32x4{0.f, 0.f, 0.f, 0.f};

#pragma unroll 1
    for (int kc = 0; kc < NKC; ++kc) {
        const int t  = kc * 2 + (g >> 1);       // 27 = pad tap: wBf is zero there
        const int tz = t / 9, ty = (t / 3) % 3, tx = t % 3;
        const int zp = d + tz + (PADZ - 1);     // in-bounds by construction
        const int yp = h + ty + (PADY - 1);
        const int rowbase = (zp * PHH + yp) * PWW;
        const int xoff = tx + (PADX - 1);
        const int half = g & 1;

        f16x8 bfr[NNT];
#pragma unroll
        for (int n = 0; n < NNT; ++n) bfr[n] = wBf[(kc * NNT + n) * 64 + lane];

#pragma unroll
        for (int mi = 0; mi < 4; ++mi) {
            const int xpc = (wave * 4 + mi) * 16 + col + xoff;
            const f16x8 av = xp16[(size_t)(rowbase + xpc) * 2 + half];
#pragma unroll
            for (int n = 0; n < NNT; ++n)
                acc[mi][n] = __builtin_amdgcn_mfma_f32_16x16x32_f16(
                    av, bfr[n], acc[mi][n], 0, 0, 0);
        }
    }

    // ---- phase 1b: +off_b, tanh, scale -> LDS ----
#pragma unroll
    for (int n = 0; n < NNT; ++n) {
        const int j = n * 16 + col;
        if (j < NOFF) {
            const float ob = off_b[j];
            const float sc = (j % 3 == 2) ? 2.f : 4.f;
#pragma unroll
            for (int mi = 0; mi < 4; ++mi) {
#pragma unroll
                for (int r = 0; r < 4; ++r) {
                    const int vl = (wave * 4 + mi) * 16 + g * 4 + r;
                    loff[vl * 84 + j] =
                        (_Float16)(fast_tanh(acc[mi][n][r] + ob) * sc);
                }
            }
        }
    }
    __syncthreads();

    // ---- phase 2/3: sample in B-fragment layout + MFMA contraction ----
    f32x4 acc3[2][4];
#pragma unroll
    for (int mo = 0; mo < 2; ++mo)
#pragma unroll
        for (int nv = 0; nv < 4; ++nv) acc3[mo][nv] = f32x4{0.f, 0.f, 0.f, 0.f};

    const int half = g & 1;

#pragma unroll 1
    for (int kc = 0; kc < NKC; ++kc) {
        const int myTap = kc * 2 + (g >> 1);
        const int tA = min(myTap, KK - 1);      // pad tap: weight=0 via wW3

        const f16x8 aw0 = wW3[(kc * 2 + 0) * 64 + lane];
        const f16x8 aw1 = wW3[(kc * 2 + 1) * 64 + lane];

        const int rx = tA % 3 - 1, ry = (tA / 3) % 3 - 1, rz = tA / 9 - 1;
        const float gyb = (float)(h + 1 + ry);
        const float gzb = (float)(d + 1 + rz);
        const int loffBase = tA * 3;

#pragma unroll
        for (int nv = 0; nv < 4; ++nv) {
            const int wv = wave * 64 + nv * 16 + col;   // local w of my column

            const float dxo = (float)loff[wv * 84 + loffBase + 0];
            const float dyo = (float)loff[wv * 84 + loffBase + 1];
            const float dzo = (float)loff[wv * 84 + loffBase + 2];

            const float gx = (float)(wv + 1 + rx) + dxo;
            const float gy = gyb + dyo;
            const float gz = gzb + dzo;
            const float fx0f = floorf(gx), fy0f = floorf(gy), fz0f = floorf(gz);
            const float fx = gx - fx0f, fy = gy - fy0f, fz = gz - fz0f;
            const float ifx = 1.f - fx, ify = 1.f - fy, ifz = 1.f - fz;

            // padded corner-0 index: no validity, no clamps
            const int xp0 = (int)fx0f + (PADX - 1);
            const int yp0 = (int)fy0f + (PADY - 1);
            const int zp0 = (int)fz0f + (PADZ - 1);
            const int base = (zp0 * PHH + yp0) * PWW + xp0;

            // corner weights: pure products (zero ring supplies the zeros)
            const float wz0y0 = ifz * ify, wz0y1 = ifz * fy;
            const float wz1y0 = fz * ify,  wz1y1 = fz * fy;
            float cw[8];
            cw[0] = wz0y0 * ifx; cw[1] = wz0y0 * fx;
            cw[2] = wz0y1 * ifx; cw[3] = wz0y1 * fx;
            cw[4] = wz1y0 * ifx; cw[5] = wz1y0 * fx;
            cw[6] = wz1y1 * ifx; cw[7] = wz1y1 * fx;

            f16x8 cv[8];
            cv[0] = xp16[(size_t)(base) * 2 + half];
            cv[1] = xp16[(size_t)(base + 1) * 2 + half];
            cv[2] = xp16[(size_t)(base + PWW) * 2 + half];
            cv[3] = xp16[(size_t)(base + PWW + 1) * 2 + half];
            cv[4] = xp16[(size_t)(base + PZS) * 2 + half];
            cv[5] = xp16[(size_t)(base + PZS + 1) * 2 + half];
            cv[6] = xp16[(size_t)(base + PZS + PWW) * 2 + half];
            cv[7] = xp16[(size_t)(base + PZS + PWW + 1) * 2 + half];

            union { f16x8 v; h2 s[4]; } sf;
#pragma unroll
            for (int p = 0; p < 4; ++p) { sf.s[p][0] = (_Float16)0.f; sf.s[p][1] = (_Float16)0.f; }
#pragma unroll
            for (int c = 0; c < 8; ++c) {
                const _Float16 wh = (_Float16)cw[c];
                h2 w2; w2[0] = wh; w2[1] = wh;
                const h2* cvp = (const h2*)&cv[c];
#pragma unroll
                for (int p = 0; p < 4; ++p)
                    sf.s[p] = sf.s[p] + w2 * cvp[p];
            }

            acc3[0][nv] = __builtin_amdgcn_mfma_f32_16x16x32_f16(
                aw0, sf.v, acc3[0][nv], 0, 0, 0);
            acc3[1][nv] = __builtin_amdgcn_mfma_f32_16x16x32_f16(
                aw1, sf.v, acc3[1][nv], 0, 0, 0);
        }
    }

    // ---- store: D row = o-in-tile (4g+r), col = vox (16-lane contiguous) ----
    const int rowBase = (d * HH + h) * WW;
#pragma unroll
    for (int mo = 0; mo < 2; ++mo) {
#pragma unroll
        for (int r = 0; r < 4; ++r) {
            const int o = mo * 16 + 4 * g + r;
            const float b = bias[o];
#pragma unroll
            for (int nv = 0; nv < 4; ++nv) {
                const int wv = wave * 64 + nv * 16 + col;
                out[(size_t)o * DHW + rowBase + wv] = acc3[mo][nv][r] + b;
            }
        }
    }
}

// ---------------------------------------------------------------------------
// Fallback (ws too small): fully fp32, original x layout.
// ---------------------------------------------------------------------------
__global__ __launch_bounds__(128) void deform_fallback(
    const float* __restrict__ x,
    const float* __restrict__ weight,
    const float* __restrict__ bias,
    const float* __restrict__ off_w,
    const float* __restrict__ off_b,
    float* __restrict__ out)
{
    const int w = threadIdx.x;
    const int h = blockIdx.x & (HH - 1);
    const int d = blockIdx.x >> 7;

    float outacc[COUT];
#pragma unroll
    for (int o = 0; o < COUT; ++o) outacc[o] = 0.f;

    for (int k = 0; k < KK; ++k) {
        float a0 = 0.f, a1 = 0.f, a2 = 0.f;
        const float* w0 = off_w + (size_t)(k * 3 + 0) * (CIN * KK);
        const float* w1 = off_w + (size_t)(k * 3 + 1) * (CIN * KK);
        const float* w2 = off_w + (size_t)(k * 3 + 2) * (CIN * KK);
        for (int ci = 0; ci < CIN; ++ci) {
            const float* xc = x + (size_t)ci * DHW;
#pragma unroll
            for (int t = 0; t < KK; ++t) {
                const int tz = t / 9, ty = (t / 3) % 3, tx = t % 3;
                const int zz = d + tz - 1, yy = h + ty - 1, xx = w + tx - 1;
                const bool ok = (unsigned)zz < (unsigned)DD &&
                                (unsigned)yy < (unsigned)HH &&
                                (unsigned)xx < (unsigned)WW;
                const float v = ok ? xc[(zz * HH + yy) * WW + xx] : 0.f;
                a0 = fmaf(v, w0[ci * KK + t], a0);
                a1 = fmaf(v, w1[ci * KK + t], a1);
                a2 = fmaf(v, w2[ci * KK + t], a2);
            }
        }
        const float dxo = fast_tanh(a0 + off_b[k * 3 + 0]) * 4.f;
        const float dyo = fast_tanh(a1 + off_b[k * 3 + 1]) * 4.f;
        const float dzo = fast_tanh(a2 + off_b[k * 3 + 2]) * 2.f;

        const int rx = k % 3 - 1, ry = (k / 3) % 3 - 1, rz = k / 9 - 1;
        const float gx = (float)(w + 1 + rx) + dxo;
        const float gy = (float)(h + 1 + ry) + dyo;
        const float gz = (float)(d + 1 + rz) + dzo;
        const float fx0 = floorf(gx), fy0 = floorf(gy), fz0 = floorf(gz);
        const float fx = gx - fx0, fy = gy - fy0, fz = gz - fz0;
        const int x0 = (int)fx0 - 1, y0 = (int)fy0 - 1, z0 = (int)fz0 - 1;

        float samp[CIN];
#pragma unroll
        for (int ci = 0; ci < CIN; ++ci) samp[ci] = 0.f;
#pragma unroll
        for (int c = 0; c < 8; ++c) {
            const int cx = x0 + (c & 1);
            const int cy = y0 + ((c >> 1) & 1);
            const int cz = z0 + (c >> 2);
            const float wt = ((c & 1) ? fx : 1.f - fx) *
                             (((c >> 1) & 1) ? fy : 1.f - fy) *
                             ((c >> 2) ? fz : 1.f - fz);
            if ((unsigned)cx < (unsigned)WW && (unsigned)cy < (unsigned)HH &&
                (unsigned)cz < (unsigned)DD) {
                const float* p = x + ((cz * HH) + cy) * WW + cx;
#pragma unroll
                for (int ci = 0; ci < 16; ++ci)
                    samp[ci] = fmaf(wt, p[(size_t)ci * DHW], samp[ci]);
            }
        }
#pragma unroll
        for (int o = 0; o < COUT; ++o) {
            float s = 0.f;
#pragma unroll
            for (int ci = 0; ci < 16; ++ci)
                s = fmaf(weight[(o * CIN + ci) * KK + k], samp[ci], s);
            outacc[o] += s;
        }
    }
    const int vox = (d * HH + h) * WW + w;
#pragma unroll
    for (int o = 0; o < COUT; ++o)
        out[(size_t)o * DHW + vox] = outacc[o] + bias[o];
}

extern "C" void kernel_launch(void* const* d_in, const int* in_sizes, int n_in,
                              void* d_out, int out_size, void* d_ws, size_t ws_size,
                              hipStream_t stream) {
    const float* x      = (const float*)d_in[0];
    const float* weight = (const float*)d_in[1];
    const float* bias   = (const float*)d_in[2];
    const float* off_w  = (const float*)d_in[3];
    const float* off_b  = (const float*)d_in[4];
    float* out = (float*)d_out;

    if (ws_size >= WS_NEED) {
        H16* xp = (H16*)d_ws;
        _Float16* wBf = (_Float16*)((char*)d_ws + WBF_OFF);
        _Float16* wW3 = (_Float16*)((char*)d_ws + WW3_OFF);
        pack_w<<<(WBF_ELEMS + 255) / 256, 256, 0, stream>>>(off_w, weight, wBf, wW3);
        pad_x_h<<<PDD * PHH, 192, 0, stream>>>(x, xp);
        deform_full<<<DD * HH, 128, 0, stream>>>((const f16x8*)xp, (const f16x8*)wBf,
                                                 (const f16x8*)wW3, off_b, bias, out);
    } else {
        deform_fallback<<<DD * HH, 128, 0, stream>>>(x, weight, bias, off_w, off_b, out);
    }
}

// Round 11
// 249.994 us; speedup vs baseline: 1.0259x; 1.0259x over previous
//
#include <hip/hip_runtime.h>

#define DD 16
#define HH 128
#define WW 128
#define DHW (DD * HH * WW)   // 262144
#define CIN 16
#define COUT 32
#define KK 27
#define NOFF 81
#define NKC 14               // K-chunks of 32 over (tap,ci); taps padded 27->28
#define NNT 6                // phase-1 n-tiles of 16 over 81->96

typedef _Float16 h2    __attribute__((ext_vector_type(2)));
typedef _Float16 f16x8 __attribute__((ext_vector_type(8)));
typedef float    f32x4 __attribute__((ext_vector_type(4)));
struct H16 { h2 v[8]; };     // 16 fp16 channels = 32 B

// ---- ws layout ----
// [0, 8MB)    xt  : fp16 [vox][16]
// [8MB,+84K)  wBf : off_w in MFMA B-frag order [kc][n][lane][8]   (phase 1)
// [next,+28K) wW3 : weight in MFMA A-frag order [kc][mo][lane][8] (phase 3)
#define XT_BYTES   ((size_t)DHW * CIN * 2)            // 8 MiB
#define WBF_OFF    XT_BYTES
#define WBF_ELEMS  (NKC * NNT * 64 * 8)               // 43008 halves
#define WW3_OFF    (WBF_OFF + (size_t)WBF_ELEMS * 2)
#define WW3_ELEMS  (NKC * 2 * 64 * 8)                 // 14336 halves
#define WS_NEED    (WW3_OFF + (size_t)WW3_ELEMS * 2)

__device__ __forceinline__ float fast_tanh(float s) {
    float e = __expf(fminf(2.f * s, 80.f));
    return (e - 1.f) * __builtin_amdgcn_rcpf(e + 1.f);
}

// x [ci][vox] fp32  ->  xt [vox][ci] fp16
__global__ __launch_bounds__(256) void transpose_x_h(const float* __restrict__ x,
                                                     H16* __restrict__ xt) {
    int vox = blockIdx.x * 256 + threadIdx.x;
    if (vox >= DHW) return;
    H16 o;
#pragma unroll
    for (int p = 0; p < 8; ++p) {
        o.v[p][0] = (_Float16)x[(size_t)(2 * p) * DHW + vox];
        o.v[p][1] = (_Float16)x[(size_t)(2 * p + 1) * DHW + vox];
    }
    xt[vox] = o;
}

// Pack off_w into phase-1 B fragments and weight into phase-3 A fragments.
__global__ __launch_bounds__(256) void pack_w(const float* __restrict__ off_w,
                                              const float* __restrict__ weight,
                                              _Float16* __restrict__ wBf,
                                              _Float16* __restrict__ wW3) {
    int idx = blockIdx.x * 256 + threadIdx.x;
    if (idx < WBF_ELEMS) {
        int i    = idx & 7;
        int lane = (idx >> 3) & 63;
        int fn   = idx >> 9;            // kc*NNT + n
        int n    = fn % NNT;
        int kc   = fn / NNT;
        int g    = lane >> 4;
        int t    = kc * 2 + (g >> 1);
        int ci   = (g & 1) * 8 + i;
        int j    = n * 16 + (lane & 15);
        float v = 0.f;
        if (t < KK && j < NOFF) v = off_w[(size_t)(j * CIN + ci) * KK + t];
        wBf[idx] = (_Float16)v;
    }
    if (idx < WW3_ELEMS) {
        int i    = idx & 7;
        int lane = (idx >> 3) & 63;
        int fm   = idx >> 9;            // kc*2 + mo
        int mo   = fm & 1;
        int kc   = fm >> 1;
        int g    = lane >> 4;
        int t    = kc * 2 + (g >> 1);
        int ci   = (g & 1) * 8 + i;
        int o    = mo * 16 + (lane & 15);
        float v = 0.f;
        if (t < KK) v = weight[(size_t)(o * CIN + ci) * KK + t];
        wW3[idx] = (_Float16)v;
    }
}

// ---------------------------------------------------------------------------
// Fused kernel (R5 structure), register-occupancy edition:
//  - phase 1 N-split into two passes (acc peak 96 -> 48 floats)
//  - LDS 19968B (stride 78; tap-26 channels stashed into slots 0..2 after kc=0)
//  - wave_barrier instead of __syncthreads (loff exchange is intra-wave)
//  - __launch_bounds__(128,4): target 4 waves/SIMD residency
// ---------------------------------------------------------------------------
__global__ __launch_bounds__(128, 4) void deform_full(
    const f16x8* __restrict__ xt16,   // 2 per voxel (8 ch each)
    const f16x8* __restrict__ wBf,    // phase-1 B fragments
    const f16x8* __restrict__ wW3,    // phase-3 A fragments
    const float* __restrict__ off_b,  // [81]
    const float* __restrict__ bias,   // [32]
    float* __restrict__ out)          // [32][DHW]
{
    // offsets: [local vox][78] fp16; taps 0..25 at j=t*3+c, tap 26 -> slots 0..2
    __shared__ _Float16 loff[128 * 78];

    const int lb = ((blockIdx.x & 7) << 8) | (blockIdx.x >> 3);  // XCD swizzle
    const int h = lb & (HH - 1);
    const int d = lb >> 7;
    const int lane = threadIdx.x & 63;
    const int wave = threadIdx.x >> 6;
    const int g = lane >> 4;
    const int col = lane & 15;
    const int half = g & 1;

    _Float16 keepA[16];   // ch78 (col==14) / ch79 (col==15) for this lane's 16 voxels
    _Float16 keepB[16];   // ch80 (col==0)

    // ---- phase 1: offset conv as implicit GEMM, N split into 2 passes ----
#pragma unroll 1
    for (int pass = 0; pass < 2; ++pass) {
        f32x4 acc[4][3];
#pragma unroll
        for (int mi = 0; mi < 4; ++mi)
#pragma unroll
            for (int nn = 0; nn < 3; ++nn) acc[mi][nn] = f32x4{0.f, 0.f, 0.f, 0.f};

#pragma unroll 1
        for (int kc = 0; kc < NKC; ++kc) {
            const int t  = kc * 2 + (g >> 1);
            const int tz = t / 9, ty = (t / 3) % 3, tx = t % 3;
            const int zz = d + tz - 1, yy = h + ty - 1;
            const bool okzy = (t < KK) && ((unsigned)zz < (unsigned)DD) &&
                              ((unsigned)yy < (unsigned)HH);
            const int zc = min(max(zz, 0), DD - 1);
            const int yc = min(max(yy, 0), HH - 1);
            const int rowbase = (zc * HH + yc) * WW;
            const int txm1 = tx - 1;

            f16x8 bfr[3];
#pragma unroll
            for (int nn = 0; nn < 3; ++nn)
                bfr[nn] = wBf[(kc * NNT + pass * 3 + nn) * 64 + lane];

#pragma unroll
            for (int mi = 0; mi < 4; ++mi) {
                const int xx = (wave * 4 + mi) * 16 + col + txm1;
                const bool ok = okzy && ((unsigned)xx < (unsigned)WW);
                const int xc = min(max(xx, 0), WW - 1);
                union { f16x8 v; uint4 u; } au;
                au.v = xt16[(size_t)(rowbase + xc) * 2 + half];
                if (!ok) au.u = make_uint4(0u, 0u, 0u, 0u);
#pragma unroll
                for (int nn = 0; nn < 3; ++nn)
                    acc[mi][nn] = __builtin_amdgcn_mfma_f32_16x16x32_f16(
                        au.v, bfr[nn], acc[mi][nn], 0, 0, 0);
            }
        }

        // ---- phase 1b (per pass): +off_b, tanh, scale -> LDS / keep regs ----
#pragma unroll
        for (int nn = 0; nn < 3; ++nn) {
            const int j = (pass * 3 + nn) * 16 + col;
            const float ob = (j < NOFF) ? off_b[j] : 0.f;
            const float sc = (j % 3 == 2) ? 2.f : 4.f;
#pragma unroll
            for (int mi = 0; mi < 4; ++mi) {
#pragma unroll
                for (int r = 0; r < 4; ++r) {
                    const _Float16 val =
                        (_Float16)(fast_tanh(acc[mi][nn][r] + ob) * sc);
                    if (nn == 1 && pass == 1) keepA[mi * 4 + r] = val;
                    if (nn == 2 && pass == 1) keepB[mi * 4 + r] = val;
                    if (j < 78) {
                        const int vl = (wave * 4 + mi) * 16 + g * 4 + r;
                        loff[vl * 78 + j] = val;
                    }
                }
            }
        }
    }
    __builtin_amdgcn_wave_barrier();   // intra-wave LDS exchange (DS in-order)

    // ---- phase 2/3: sample in B-fragment layout + MFMA contraction ----
    f32x4 acc3[2][4];
#pragma unroll
    for (int mo = 0; mo < 2; ++mo)
#pragma unroll
        for (int nv = 0; nv < 4; ++nv) acc3[mo][nv] = f32x4{0.f, 0.f, 0.f, 0.f};

    auto kcBody = [&](int kc) {
        const int myTap = kc * 2 + (g >> 1);
        const int tA = min(myTap, KK - 1);
        // tap 26 remapped to LDS slots 0..2 (stashed after kc==0)
        const int loffBase = (tA == KK - 1) ? 0 : tA * 3;

        const f16x8 aw0 = wW3[(kc * 2 + 0) * 64 + lane];
        const f16x8 aw1 = wW3[(kc * 2 + 1) * 64 + lane];

        const int rx = tA % 3 - 1, ry = (tA / 3) % 3 - 1, rz = tA / 9 - 1;

#pragma unroll
        for (int nv = 0; nv < 4; ++nv) {
            const int wv = wave * 64 + nv * 16 + col;   // local w of my column

            const float dxo = (float)loff[wv * 78 + loffBase + 0];
            const float dyo = (float)loff[wv * 78 + loffBase + 1];
            const float dzo = (float)loff[wv * 78 + loffBase + 2];

            const float gx = (float)(wv + 1 + rx) + dxo;
            const float gy = (float)(h + 1 + ry) + dyo;
            const float gz = (float)(d + 1 + rz) + dzo;
            const float fx0f = floorf(gx), fy0f = floorf(gy), fz0f = floorf(gz);
            const float fx = gx - fx0f, fy = gy - fy0f, fz = gz - fz0f;
            const int x0 = (int)fx0f - 1, y0 = (int)fy0f - 1, z0 = (int)fz0f - 1;
            const float ifx = 1.f - fx, ify = 1.f - fy, ifz = 1.f - fz;

            // per-corner independent validity/clamp (max ILP — R5 form)
            float cw[8];
            int cidx[8];
#pragma unroll
            for (int c = 0; c < 8; ++c) {
                const int cx = x0 + (c & 1);
                const int cy = y0 + ((c >> 1) & 1);
                const int cz = z0 + (c >> 2);
                const bool ok = (unsigned)cx < (unsigned)WW &&
                                (unsigned)cy < (unsigned)HH &&
                                (unsigned)cz < (unsigned)DD;
                const float wt = ((c & 1) ? fx : ifx) *
                                 (((c >> 1) & 1) ? fy : ify) *
                                 ((c >> 2) ? fz : ifz);
                cw[c] = ok ? wt : 0.f;
                const int cxc = min(max(cx, 0), WW - 1);
                const int cyc = min(max(cy, 0), HH - 1);
                const int czc = min(max(cz, 0), DD - 1);
                cidx[c] = (czc * HH + cyc) * WW + cxc;
            }

            f16x8 cv[8];
#pragma unroll
            for (int c = 0; c < 8; ++c)
                cv[c] = xt16[(size_t)cidx[c] * 2 + half];

            union { f16x8 v; h2 s[4]; } sf;
#pragma unroll
            for (int p = 0; p < 4; ++p) { sf.s[p][0] = (_Float16)0.f; sf.s[p][1] = (_Float16)0.f; }
#pragma unroll
            for (int c = 0; c < 8; ++c) {
                const _Float16 wh = (_Float16)cw[c];
                h2 w2; w2[0] = wh; w2[1] = wh;
                const h2* cvp = (const h2*)&cv[c];
#pragma unroll
                for (int p = 0; p < 4; ++p)
                    sf.s[p] = sf.s[p] + w2 * cvp[p];
            }

            acc3[0][nv] = __builtin_amdgcn_mfma_f32_16x16x32_f16(
                aw0, sf.v, acc3[0][nv], 0, 0, 0);
            acc3[1][nv] = __builtin_amdgcn_mfma_f32_16x16x32_f16(
                aw1, sf.v, acc3[1][nv], 0, 0, 0);
        }
    };

    // kc = 0 consumes LDS slots 0..5 (taps 0,1); then stash tap-26 into 0..2
    kcBody(0);
    {
        const bool wr = (col == 0) || (col == 14) || (col == 15);
        if (wr) {
            const int jj = (col == 14) ? 0 : ((col == 15) ? 1 : 2);
#pragma unroll
            for (int mi = 0; mi < 4; ++mi) {
#pragma unroll
                for (int r = 0; r < 4; ++r) {
                    const int vl = (wave * 4 + mi) * 16 + g * 4 + r;
                    const _Float16 v =
                        (col == 0) ? keepB[mi * 4 + r] : keepA[mi * 4 + r];
                    loff[vl * 78 + jj] = v;
                }
            }
        }
    }
    __builtin_amdgcn_wave_barrier();

#pragma unroll 1
    for (int kc = 1; kc < NKC; ++kc) kcBody(kc);

    // ---- store: D row = o-in-tile (4g+r), col = vox (16-lane contiguous) ----
    const int rowBase = (d * HH + h) * WW;
#pragma unroll
    for (int mo = 0; mo < 2; ++mo) {
#pragma unroll
        for (int r = 0; r < 4; ++r) {
            const int o = mo * 16 + 4 * g + r;
            const float b = bias[o];
#pragma unroll
            for (int nv = 0; nv < 4; ++nv) {
                const int wv = wave * 64 + nv * 16 + col;
                out[(size_t)o * DHW + rowBase + wv] = acc3[mo][nv][r] + b;
            }
        }
    }
}

// ---------------------------------------------------------------------------
// Fallback (ws too small): fully fp32, original x layout.
// ---------------------------------------------------------------------------
__global__ __launch_bounds__(128) void deform_fallback(
    const float* __restrict__ x,
    const float* __restrict__ weight,
    const float* __restrict__ bias,
    const float* __restrict__ off_w,
    const float* __restrict__ off_b,
    float* __restrict__ out)
{
    const int w = threadIdx.x;
    const int h = blockIdx.x & (HH - 1);
    const int d = blockIdx.x >> 7;

    float outacc[COUT];
#pragma unroll
    for (int o = 0; o < COUT; ++o) outacc[o] = 0.f;

    for (int k = 0; k < KK; ++k) {
        float a0 = 0.f, a1 = 0.f, a2 = 0.f;
        const float* w0 = off_w + (size_t)(k * 3 + 0) * (CIN * KK);
        const float* w1 = off_w + (size_t)(k * 3 + 1) * (CIN * KK);
        const float* w2 = off_w + (size_t)(k * 3 + 2) * (CIN * KK);
        for (int ci = 0; ci < CIN; ++ci) {
            const float* xc = x + (size_t)ci * DHW;
#pragma unroll
            for (int t = 0; t < KK; ++t) {
                const int tz = t / 9, ty = (t / 3) % 3, tx = t % 3;
                const int zz = d + tz - 1, yy = h + ty - 1, xx = w + tx - 1;
                const bool ok = (unsigned)zz < (unsigned)DD &&
                                (unsigned)yy < (unsigned)HH &&
                                (unsigned)xx < (unsigned)WW;
                const float v = ok ? xc[(zz * HH + yy) * WW + xx] : 0.f;
                a0 = fmaf(v, w0[ci * KK + t], a0);
                a1 = fmaf(v, w1[ci * KK + t], a1);
                a2 = fmaf(v, w2[ci * KK + t], a2);
            }
        }
        const float dxo = fast_tanh(a0 + off_b[k * 3 + 0]) * 4.f;
        const float dyo = fast_tanh(a1 + off_b[k * 3 + 1]) * 4.f;
        const float dzo = fast_tanh(a2 + off_b[k * 3 + 2]) * 2.f;

        const int rx = k % 3 - 1, ry = (k / 3) % 3 - 1, rz = k / 9 - 1;
        const float gx = (float)(w + 1 + rx) + dxo;
        const float gy = (float)(h + 1 + ry) + dyo;
        const float gz = (float)(d + 1 + rz) + dzo;
        const float fx0 = floorf(gx), fy0 = floorf(gy), fz0 = floorf(gz);
        const float fx = gx - fx0, fy = gy - fy0, fz = gz - fz0;
        const int x0 = (int)fx0 - 1, y0 = (int)fy0 - 1, z0 = (int)fz0 - 1;

        float samp[CIN];
#pragma unroll
        for (int ci = 0; ci < CIN; ++ci) samp[ci] = 0.f;
#pragma unroll
        for (int c = 0; c < 8; ++c) {
            const int cx = x0 + (c & 1);
            const int cy = y0 + ((c >> 1) & 1);
            const int cz = z0 + (c >> 2);
            const float wt = ((c & 1) ? fx : 1.f - fx) *
                             (((c >> 1) & 1) ? fy : 1.f - fy) *
                             ((c >> 2) ? fz : 1.f - fz);
            if ((unsigned)cx < (unsigned)WW && (unsigned)cy < (unsigned)HH &&
                (unsigned)cz < (unsigned)DD) {
                const float* p = x + ((cz * HH) + cy) * WW + cx;
#pragma unroll
                for (int ci = 0; ci < 16; ++ci)
                    samp[ci] = fmaf(wt, p[(size_t)ci * DHW], samp[ci]);
            }
        }
#pragma unroll
        for (int o = 0; o < COUT; ++o) {
            float s = 0.f;
#pragma unroll
            for (int ci = 0; ci < 16; ++ci)
                s = fmaf(weight[(o * CIN + ci) * KK + k], samp[ci], s);
            outacc[o] += s;
        }
    }
    const int vox = (d * HH + h) * WW + w;
#pragma unroll
    for (int o = 0; o < COUT; ++o)
        out[(size_t)o * DHW + vox] = outacc[o] + bias[o];
}

extern "C" void kernel_launch(void* const* d_in, const int* in_sizes, int n_in,
                              void* d_out, int out_size, void* d_ws, size_t ws_size,
                              hipStream_t stream) {
    const float* x      = (const float*)d_in[0];
    const float* weight = (const float*)d_in[1];
    const float* bias   = (const float*)d_in[2];
    const float* off_w  = (const float*)d_in[3];
    const float* off_b  = (const float*)d_in[4];
    float* out = (float*)d_out;

    if (ws_size >= WS_NEED) {
        H16* xt = (H16*)d_ws;
        _Float16* wBf = (_Float16*)((char*)d_ws + WBF_OFF);
        _Float16* wW3 = (_Float16*)((char*)d_ws + WW3_OFF);
        pack_w<<<(WBF_ELEMS + 255) / 256, 256, 0, stream>>>(off_w, weight, wBf, wW3);
        transpose_x_h<<<(DHW + 255) / 256, 256, 0, stream>>>(x, xt);
        deform_full<<<DD * HH, 128, 0, stream>>>((const f16x8*)xt, (const f16x8*)wBf,
                                                 (const f16x8*)wW3, off_b, bias, out);
    } else {
        deform_fallback<<<DD * HH, 128, 0, stream>>>(x, weight, bias, off_w, off_b, out);
    }
}

// Round 12
// 183.499 us; speedup vs baseline: 1.3976x; 1.3624x over previous
//
#include <hip/hip_runtime.h>

#define DD 16
#define HH 128
#define WW 128
#define DHW (DD * HH * WW)   // 262144
#define CIN 16
#define COUT 32
#define KK 27
#define NOFF 81
#define NKC 14               // K-chunks of 32 over (tap,ci); taps padded 27->28
#define NNT 6                // phase-1 n-tiles of 16 over 81->96

typedef _Float16 h2    __attribute__((ext_vector_type(2)));
typedef _Float16 f16x8 __attribute__((ext_vector_type(8)));
typedef float    f32x4 __attribute__((ext_vector_type(4)));
struct H16 { h2 v[8]; };     // 16 fp16 channels = 32 B

// ---- ws layout ----
// [0, 8MB)    xt  : fp16 [vox][16]
// [8MB,+84K)  wBf : off_w in MFMA B-frag order [kc][n][lane][8]   (phase 1)
// [next,+28K) wW3 : weight in MFMA A-frag order [kc][mo][lane][8] (phase 3)
#define XT_BYTES   ((size_t)DHW * CIN * 2)            // 8 MiB
#define WBF_OFF    XT_BYTES
#define WBF_ELEMS  (NKC * NNT * 64 * 8)               // 43008 halves
#define WW3_OFF    (WBF_OFF + (size_t)WBF_ELEMS * 2)
#define WW3_ELEMS  (NKC * 2 * 64 * 8)                 // 14336 halves
#define WS_NEED    (WW3_OFF + (size_t)WW3_ELEMS * 2)

__device__ __forceinline__ float fast_tanh(float s) {
    float e = __expf(fminf(2.f * s, 80.f));
    return (e - 1.f) * __builtin_amdgcn_rcpf(e + 1.f);
}

// x [ci][vox] fp32  ->  xt [vox][ci] fp16
__global__ __launch_bounds__(256) void transpose_x_h(const float* __restrict__ x,
                                                     H16* __restrict__ xt) {
    int vox = blockIdx.x * 256 + threadIdx.x;
    if (vox >= DHW) return;
    H16 o;
#pragma unroll
    for (int p = 0; p < 8; ++p) {
        o.v[p][0] = (_Float16)x[(size_t)(2 * p) * DHW + vox];
        o.v[p][1] = (_Float16)x[(size_t)(2 * p + 1) * DHW + vox];
    }
    xt[vox] = o;
}

// Pack off_w into phase-1 B fragments and weight into phase-3 A fragments.
__global__ __launch_bounds__(256) void pack_w(const float* __restrict__ off_w,
                                              const float* __restrict__ weight,
                                              _Float16* __restrict__ wBf,
                                              _Float16* __restrict__ wW3) {
    int idx = blockIdx.x * 256 + threadIdx.x;
    if (idx < WBF_ELEMS) {
        int i    = idx & 7;
        int lane = (idx >> 3) & 63;
        int fn   = idx >> 9;            // kc*NNT + n
        int n    = fn % NNT;
        int kc   = fn / NNT;
        int g    = lane >> 4;
        int t    = kc * 2 + (g >> 1);
        int ci   = (g & 1) * 8 + i;
        int j    = n * 16 + (lane & 15);
        float v = 0.f;
        if (t < KK && j < NOFF) v = off_w[(size_t)(j * CIN + ci) * KK + t];
        wBf[idx] = (_Float16)v;
    }
    if (idx < WW3_ELEMS) {
        int i    = idx & 7;
        int lane = (idx >> 3) & 63;
        int fm   = idx >> 9;            // kc*2 + mo
        int mo   = fm & 1;
        int kc   = fm >> 1;
        int g    = lane >> 4;
        int t    = kc * 2 + (g >> 1);
        int ci   = (g & 1) * 8 + i;
        int o    = mo * 16 + (lane & 15);
        float v = 0.f;
        if (t < KK) v = weight[(size_t)(o * CIN + ci) * KK + t];
        wW3[idx] = (_Float16)v;
    }
}

// ---------------------------------------------------------------------------
// Fused kernel, R5 inner loops, M-SPLIT across 4 waves (256 threads/block,
// same 128 voxels/block): per-wave state halves (acc 96->48 f32, acc3 32->16)
// so the allocator lands ~4 waves/SIMD naturally — no forced bounds, no
// spills, no extra memory traffic. loff exchange remains intra-wave.
// ---------------------------------------------------------------------------
__global__ __launch_bounds__(256) void deform_full(
    const f16x8* __restrict__ xt16,   // 2 per voxel (8 ch each)
    const f16x8* __restrict__ wBf,    // phase-1 B fragments
    const f16x8* __restrict__ wW3,    // phase-3 A fragments
    const float* __restrict__ off_b,  // [81]
    const float* __restrict__ bias,   // [32]
    float* __restrict__ out)          // [32][DHW]
{
    // offsets: [local w][tap*3+comp] fp16, row stride 84 halves (168B)
    __shared__ _Float16 loff[128 * 84];

    const int lb = ((blockIdx.x & 7) << 8) | (blockIdx.x >> 3);  // XCD swizzle
    const int h = lb & (HH - 1);
    const int d = lb >> 7;
    const int lane = threadIdx.x & 63;
    const int wave = threadIdx.x >> 6;     // 0..3, owns 32 voxels
    const int g = lane >> 4;
    const int col = lane & 15;
    const int half = g & 1;

    // ---- phase 1: offset conv as implicit GEMM (M=32 per wave) ----
    f32x4 acc[2][NNT];
#pragma unroll
    for (int mi = 0; mi < 2; ++mi)
#pragma unroll
        for (int n = 0; n < NNT; ++n) acc[mi][n] = f32x4{0.f, 0.f, 0.f, 0.f};

#pragma unroll 1
    for (int kc = 0; kc < NKC; ++kc) {
        const int t  = kc * 2 + (g >> 1);
        const int tz = t / 9, ty = (t / 3) % 3, tx = t % 3;
        const int zz = d + tz - 1, yy = h + ty - 1;
        const bool okzy = (t < KK) && ((unsigned)zz < (unsigned)DD) &&
                          ((unsigned)yy < (unsigned)HH);
        const int zc = min(max(zz, 0), DD - 1);
        const int yc = min(max(yy, 0), HH - 1);
        const int rowbase = (zc * HH + yc) * WW;
        const int txm1 = tx - 1;

        f16x8 bfr[NNT];
#pragma unroll
        for (int n = 0; n < NNT; ++n) bfr[n] = wBf[(kc * NNT + n) * 64 + lane];

#pragma unroll
        for (int mi = 0; mi < 2; ++mi) {
            const int xx = (wave * 2 + mi) * 16 + col + txm1;
            const bool ok = okzy && ((unsigned)xx < (unsigned)WW);
            const int xc = min(max(xx, 0), WW - 1);
            union { f16x8 v; uint4 u; } au;
            au.v = xt16[(size_t)(rowbase + xc) * 2 + half];
            if (!ok) au.u = make_uint4(0u, 0u, 0u, 0u);
#pragma unroll
            for (int n = 0; n < NNT; ++n)
                acc[mi][n] = __builtin_amdgcn_mfma_f32_16x16x32_f16(
                    au.v, bfr[n], acc[mi][n], 0, 0, 0);
        }
    }

    // ---- phase 1b: +off_b, tanh, scale -> LDS (intra-wave exchange) ----
#pragma unroll
    for (int n = 0; n < NNT; ++n) {
        const int j = n * 16 + col;
        if (j < NOFF) {
            const float ob = off_b[j];
            const float sc = (j % 3 == 2) ? 2.f : 4.f;
#pragma unroll
            for (int mi = 0; mi < 2; ++mi) {
#pragma unroll
                for (int r = 0; r < 4; ++r) {
                    const int vl = (wave * 2 + mi) * 16 + g * 4 + r;
                    loff[vl * 84 + j] =
                        (_Float16)(fast_tanh(acc[mi][n][r] + ob) * sc);
                }
            }
        }
    }
    __builtin_amdgcn_wave_barrier();   // producer/consumer same wave; DS in-order

    // ---- phase 2/3: sample in B-fragment layout + MFMA contraction ----
    f32x4 acc3[2][2];
#pragma unroll
    for (int mo = 0; mo < 2; ++mo)
#pragma unroll
        for (int nv = 0; nv < 2; ++nv) acc3[mo][nv] = f32x4{0.f, 0.f, 0.f, 0.f};

#pragma unroll 1
    for (int kc = 0; kc < NKC; ++kc) {
        const int myTap = kc * 2 + (g >> 1);
        const bool tapValid = myTap < KK;
        const int tA = tapValid ? myTap : 0;

        const f16x8 aw0 = wW3[(kc * 2 + 0) * 64 + lane];
        const f16x8 aw1 = wW3[(kc * 2 + 1) * 64 + lane];

        const int rx = tA % 3 - 1, ry = (tA / 3) % 3 - 1, rz = tA / 9 - 1;

#pragma unroll
        for (int nv = 0; nv < 2; ++nv) {
            const int wv = wave * 32 + nv * 16 + col;   // local w of my column

            float dxo = 0.f, dyo = 0.f, dzo = 0.f;
            if (tapValid) {
                dxo = (float)loff[wv * 84 + tA * 3 + 0];
                dyo = (float)loff[wv * 84 + tA * 3 + 1];
                dzo = (float)loff[wv * 84 + tA * 3 + 2];
            }

            const float gx = (float)(wv + 1 + rx) + dxo;
            const float gy = (float)(h + 1 + ry) + dyo;
            const float gz = (float)(d + 1 + rz) + dzo;
            const float fx0f = floorf(gx), fy0f = floorf(gy), fz0f = floorf(gz);
            const float fx = gx - fx0f, fy = gy - fy0f, fz = gz - fz0f;
            const int x0 = (int)fx0f - 1, y0 = (int)fy0f - 1, z0 = (int)fz0f - 1;
            const float ifx = 1.f - fx, ify = 1.f - fy, ifz = 1.f - fz;

            // per-corner independent validity/clamp (max ILP — R5 form)
            float cw[8];
            int cidx[8];
#pragma unroll
            for (int c = 0; c < 8; ++c) {
                const int cx = x0 + (c & 1);
                const int cy = y0 + ((c >> 1) & 1);
                const int cz = z0 + (c >> 2);
                const bool ok = tapValid &&
                                (unsigned)cx < (unsigned)WW &&
                                (unsigned)cy < (unsigned)HH &&
                                (unsigned)cz < (unsigned)DD;
                const float wt = ((c & 1) ? fx : ifx) *
                                 (((c >> 1) & 1) ? fy : ify) *
                                 ((c >> 2) ? fz : ifz);
                cw[c] = ok ? wt : 0.f;
                const int cxc = min(max(cx, 0), WW - 1);
                const int cyc = min(max(cy, 0), HH - 1);
                const int czc = min(max(cz, 0), DD - 1);
                cidx[c] = (czc * HH + cyc) * WW + cxc;
            }

            f16x8 cv[8];
#pragma unroll
            for (int c = 0; c < 8; ++c)
                cv[c] = xt16[(size_t)cidx[c] * 2 + half];

            union { f16x8 v; h2 s[4]; } sf;
#pragma unroll
            for (int p = 0; p < 4; ++p) { sf.s[p][0] = (_Float16)0.f; sf.s[p][1] = (_Float16)0.f; }
#pragma unroll
            for (int c = 0; c < 8; ++c) {
                const _Float16 wh = (_Float16)cw[c];
                h2 w2; w2[0] = wh; w2[1] = wh;
                const h2* cvp = (const h2*)&cv[c];
#pragma unroll
                for (int p = 0; p < 4; ++p)
                    sf.s[p] = sf.s[p] + w2 * cvp[p];
            }

            acc3[0][nv] = __builtin_amdgcn_mfma_f32_16x16x32_f16(
                aw0, sf.v, acc3[0][nv], 0, 0, 0);
            acc3[1][nv] = __builtin_amdgcn_mfma_f32_16x16x32_f16(
                aw1, sf.v, acc3[1][nv], 0, 0, 0);
        }
    }

    // ---- store: D row = o-in-tile (4g+r), col = vox (16-lane contiguous) ----
    const int rowBase = (d * HH + h) * WW;
#pragma unroll
    for (int mo = 0; mo < 2; ++mo) {
#pragma unroll
        for (int r = 0; r < 4; ++r) {
            const int o = mo * 16 + 4 * g + r;
            const float b = bias[o];
#pragma unroll
            for (int nv = 0; nv < 2; ++nv) {
                const int wv = wave * 32 + nv * 16 + col;
                out[(size_t)o * DHW + rowBase + wv] = acc3[mo][nv][r] + b;
            }
        }
    }
}

// ---------------------------------------------------------------------------
// Fallback (ws too small): fully fp32, original x layout.
// ---------------------------------------------------------------------------
__global__ __launch_bounds__(128) void deform_fallback(
    const float* __restrict__ x,
    const float* __restrict__ weight,
    const float* __restrict__ bias,
    const float* __restrict__ off_w,
    const float* __restrict__ off_b,
    float* __restrict__ out)
{
    const int w = threadIdx.x;
    const int h = blockIdx.x & (HH - 1);
    const int d = blockIdx.x >> 7;

    float outacc[COUT];
#pragma unroll
    for (int o = 0; o < COUT; ++o) outacc[o] = 0.f;

    for (int k = 0; k < KK; ++k) {
        float a0 = 0.f, a1 = 0.f, a2 = 0.f;
        const float* w0 = off_w + (size_t)(k * 3 + 0) * (CIN * KK);
        const float* w1 = off_w + (size_t)(k * 3 + 1) * (CIN * KK);
        const float* w2 = off_w + (size_t)(k * 3 + 2) * (CIN * KK);
        for (int ci = 0; ci < CIN; ++ci) {
            const float* xc = x + (size_t)ci * DHW;
#pragma unroll
            for (int t = 0; t < KK; ++t) {
                const int tz = t / 9, ty = (t / 3) % 3, tx = t % 3;
                const int zz = d + tz - 1, yy = h + ty - 1, xx = w + tx - 1;
                const bool ok = (unsigned)zz < (unsigned)DD &&
                                (unsigned)yy < (unsigned)HH &&
                                (unsigned)xx < (unsigned)WW;
                const float v = ok ? xc[(zz * HH + yy) * WW + xx] : 0.f;
                a0 = fmaf(v, w0[ci * KK + t], a0);
                a1 = fmaf(v, w1[ci * KK + t], a1);
                a2 = fmaf(v, w2[ci * KK + t], a2);
            }
        }
        const float dxo = fast_tanh(a0 + off_b[k * 3 + 0]) * 4.f;
        const float dyo = fast_tanh(a1 + off_b[k * 3 + 1]) * 4.f;
        const float dzo = fast_tanh(a2 + off_b[k * 3 + 2]) * 2.f;

        const int rx = k % 3 - 1, ry = (k / 3) % 3 - 1, rz = k / 9 - 1;
        const float gx = (float)(w + 1 + rx) + dxo;
        const float gy = (float)(h + 1 + ry) + dyo;
        const float gz = (float)(d + 1 + rz) + dzo;
        const float fx0 = floorf(gx), fy0 = floorf(gy), fz0 = floorf(gz);
        const float fx = gx - fx0, fy = gy - fy0, fz = gz - fz0;
        const int x0 = (int)fx0 - 1, y0 = (int)fy0 - 1, z0 = (int)fz0 - 1;

        float samp[CIN];
#pragma unroll
        for (int ci = 0; ci < CIN; ++ci) samp[ci] = 0.f;
#pragma unroll
        for (int c = 0; c < 8; ++c) {
            const int cx = x0 + (c & 1);
            const int cy = y0 + ((c >> 1) & 1);
            const int cz = z0 + (c >> 2);
            const float wt = ((c & 1) ? fx : 1.f - fx) *
                             (((c >> 1) & 1) ? fy : 1.f - fy) *
                             ((c >> 2) ? fz : 1.f - fz);
            if ((unsigned)cx < (unsigned)WW && (unsigned)cy < (unsigned)HH &&
                (unsigned)cz < (unsigned)DD) {
                const float* p = x + ((cz * HH) + cy) * WW + cx;
#pragma unroll
                for (int ci = 0; ci < 16; ++ci)
                    samp[ci] = fmaf(wt, p[(size_t)ci * DHW], samp[ci]);
            }
        }
#pragma unroll
        for (int o = 0; o < COUT; ++o) {
            float s = 0.f;
#pragma unroll
            for (int ci = 0; ci < 16; ++ci)
                s = fmaf(weight[(o * CIN + ci) * KK + k], samp[ci], s);
            outacc[o] += s;
        }
    }
    const int vox = (d * HH + h) * WW + w;
#pragma unroll
    for (int o = 0; o < COUT; ++o)
        out[(size_t)o * DHW + vox] = outacc[o] + bias[o];
}

extern "C" void kernel_launch(void* const* d_in, const int* in_sizes, int n_in,
                              void* d_out, int out_size, void* d_ws, size_t ws_size,
                              hipStream_t stream) {
    const float* x      = (const float*)d_in[0];
    const float* weight = (const float*)d_in[1];
    const float* bias   = (const float*)d_in[2];
    const float* off_w  = (const float*)d_in[3];
    const float* off_b  = (const float*)d_in[4];
    float* out = (float*)d_out;

    if (ws_size >= WS_NEED) {
        H16* xt = (H16*)d_ws;
        _Float16* wBf = (_Float16*)((char*)d_ws + WBF_OFF);
        _Float16* wW3 = (_Float16*)((char*)d_ws + WW3_OFF);
        pack_w<<<(WBF_ELEMS + 255) / 256, 256, 0, stream>>>(off_w, weight, wBf, wW3);
        transpose_x_h<<<(DHW + 255) / 256, 256, 0, stream>>>(x, xt);
        deform_full<<<DD * HH, 256, 0, stream>>>((const f16x8*)xt, (const f16x8*)wBf,
                                                 (const f16x8*)wW3, off_b, bias, out);
    } else {
        deform_fallback<<<DD * HH, 128, 0, stream>>>(x, weight, bias, off_w, off_b, out);
    }
}

// Round 13
// 173.555 us; speedup vs baseline: 1.4777x; 1.0573x over previous
//
#include <hip/hip_runtime.h>

#define DD 16
#define HH 128
#define WW 128
#define DHW (DD * HH * WW)   // 262144
#define CIN 16
#define COUT 32
#define KK 27
#define NOFF 81
#define NKC 14               // K-chunks of 32 over (tap,ci); taps padded 27->28
#define NNT 6                // phase-1 n-tiles of 16 over 81->96

typedef _Float16 h2    __attribute__((ext_vector_type(2)));
typedef _Float16 f16x8 __attribute__((ext_vector_type(8)));
typedef float    f32x4 __attribute__((ext_vector_type(4)));
struct H16 { h2 v[8]; };     // 16 fp16 channels = 32 B

// ---- ws layout ----
// [0, 8MB)    xt  : fp16 [vox][16]
// [8MB,+84K)  wBf : off_w in MFMA B-frag order [kc][n][lane][8]   (phase 1)
// [next,+28K) wW3 : weight in MFMA A-frag order [kc][mo][lane][8] (phase 3)
#define XT_BYTES   ((size_t)DHW * CIN * 2)            // 8 MiB
#define WBF_OFF    XT_BYTES
#define WBF_ELEMS  (NKC * NNT * 64 * 8)               // 43008 halves
#define WW3_OFF    (WBF_OFF + (size_t)WBF_ELEMS * 2)
#define WW3_ELEMS  (NKC * 2 * 64 * 8)                 // 14336 halves
#define WS_NEED    (WW3_OFF + (size_t)WW3_ELEMS * 2)

__device__ __forceinline__ float fast_tanh(float s) {
    float e = __expf(fminf(2.f * s, 80.f));
    return (e - 1.f) * __builtin_amdgcn_rcpf(e + 1.f);
}

// x [ci][vox] fp32  ->  xt [vox][ci] fp16
__global__ __launch_bounds__(256) void transpose_x_h(const float* __restrict__ x,
                                                     H16* __restrict__ xt) {
    int vox = blockIdx.x * 256 + threadIdx.x;
    if (vox >= DHW) return;
    H16 o;
#pragma unroll
    for (int p = 0; p < 8; ++p) {
        o.v[p][0] = (_Float16)x[(size_t)(2 * p) * DHW + vox];
        o.v[p][1] = (_Float16)x[(size_t)(2 * p + 1) * DHW + vox];
    }
    xt[vox] = o;
}

// Pack off_w into phase-1 B fragments and weight into phase-3 A fragments.
__global__ __launch_bounds__(256) void pack_w(const float* __restrict__ off_w,
                                              const float* __restrict__ weight,
                                              _Float16* __restrict__ wBf,
                                              _Float16* __restrict__ wW3) {
    int idx = blockIdx.x * 256 + threadIdx.x;
    if (idx < WBF_ELEMS) {
        int i    = idx & 7;
        int lane = (idx >> 3) & 63;
        int fn   = idx >> 9;            // kc*NNT + n
        int n    = fn % NNT;
        int kc   = fn / NNT;
        int g    = lane >> 4;
        int t    = kc * 2 + (g >> 1);
        int ci   = (g & 1) * 8 + i;
        int j    = n * 16 + (lane & 15);
        float v = 0.f;
        if (t < KK && j < NOFF) v = off_w[(size_t)(j * CIN + ci) * KK + t];
        wBf[idx] = (_Float16)v;
    }
    if (idx < WW3_ELEMS) {
        int i    = idx & 7;
        int lane = (idx >> 3) & 63;
        int fm   = idx >> 9;            // kc*2 + mo
        int mo   = fm & 1;
        int kc   = fm >> 1;
        int g    = lane >> 4;
        int t    = kc * 2 + (g >> 1);
        int ci   = (g & 1) * 8 + i;
        int o    = mo * 16 + (lane & 15);
        float v = 0.f;
        if (t < KK) v = weight[(size_t)(o * CIN + ci) * KK + t];
        wW3[idx] = (_Float16)v;
    }
}

// ---------------------------------------------------------------------------
// Fused kernel (R5 champion structure) + software-pipelined phase 2/3:
// next kc's loff offsets and weight fragments prefetch while the current kc's
// gathers/interp/MFMA execute (two named register sets, no runtime indexing).
// All arithmetic bit-identical to R5.
// ---------------------------------------------------------------------------
__global__ __launch_bounds__(128, 3) void deform_full(
    const f16x8* __restrict__ xt16,   // 2 per voxel (8 ch each)
    const f16x8* __restrict__ wBf,    // phase-1 B fragments
    const f16x8* __restrict__ wW3,    // phase-3 A fragments
    const float* __restrict__ off_b,  // [81]
    const float* __restrict__ bias,   // [32]
    float* __restrict__ out)          // [32][DHW]
{
    // offsets: [local w][tap*3+comp] fp16, row stride 84 halves (168B)
    __shared__ _Float16 loff[128 * 84];

    const int lb = ((blockIdx.x & 7) << 8) | (blockIdx.x >> 3);  // XCD swizzle
    const int h = lb & (HH - 1);
    const int d = lb >> 7;
    const int lane = threadIdx.x & 63;
    const int wave = threadIdx.x >> 6;
    const int g = lane >> 4;
    const int col = lane & 15;

    // ---- phase 1: offset conv as implicit GEMM ----
    f32x4 acc[4][NNT];
#pragma unroll
    for (int mi = 0; mi < 4; ++mi)
#pragma unroll
        for (int n = 0; n < NNT; ++n) acc[mi][n] = f32x4{0.f, 0.f, 0.f, 0.f};

#pragma unroll 1
    for (int kc = 0; kc < NKC; ++kc) {
        const int t  = kc * 2 + (g >> 1);
        const int tz = t / 9, ty = (t / 3) % 3, tx = t % 3;
        const int zz = d + tz - 1, yy = h + ty - 1;
        const bool okzy = (t < KK) && ((unsigned)zz < (unsigned)DD) &&
                          ((unsigned)yy < (unsigned)HH);
        const int zc = min(max(zz, 0), DD - 1);
        const int yc = min(max(yy, 0), HH - 1);
        const int rowbase = (zc * HH + yc) * WW;
        const int txm1 = tx - 1;
        const int half1 = g & 1;

        f16x8 bfr[NNT];
#pragma unroll
        for (int n = 0; n < NNT; ++n) bfr[n] = wBf[(kc * NNT + n) * 64 + lane];

#pragma unroll
        for (int mi = 0; mi < 4; ++mi) {
            const int xx = (wave * 4 + mi) * 16 + col + txm1;
            const bool ok = okzy && ((unsigned)xx < (unsigned)WW);
            const int xc = min(max(xx, 0), WW - 1);
            union { f16x8 v; uint4 u; } au;
            au.v = xt16[(size_t)(rowbase + xc) * 2 + half1];
            if (!ok) au.u = make_uint4(0u, 0u, 0u, 0u);
#pragma unroll
            for (int n = 0; n < NNT; ++n)
                acc[mi][n] = __builtin_amdgcn_mfma_f32_16x16x32_f16(
                    au.v, bfr[n], acc[mi][n], 0, 0, 0);
        }
    }

    // ---- phase 1b: +off_b, tanh, scale -> LDS ----
#pragma unroll
    for (int n = 0; n < NNT; ++n) {
        const int j = n * 16 + col;
        if (j < NOFF) {
            const float ob = off_b[j];
            const float sc = (j % 3 == 2) ? 2.f : 4.f;
#pragma unroll
            for (int mi = 0; mi < 4; ++mi) {
#pragma unroll
                for (int r = 0; r < 4; ++r) {
                    const int vl = (wave * 4 + mi) * 16 + g * 4 + r;
                    loff[vl * 84 + j] =
                        (_Float16)(fast_tanh(acc[mi][n][r] + ob) * sc);
                }
            }
        }
    }
    __syncthreads();

    // ---- phase 2/3: pipelined sample + MFMA contraction ----
    f32x4 acc3[2][4];
#pragma unroll
    for (int mo = 0; mo < 2; ++mo)
#pragma unroll
        for (int nv = 0; nv < 4; ++nv) acc3[mo][nv] = f32x4{0.f, 0.f, 0.f, 0.f};

    const int half = g & 1;

    // prefetch state: two named sets (A = even kc, B = odd kc)
    f16x8 awA0, awA1, awB0, awB1;
    float dxA[4], dyA[4], dzA[4], dxB[4], dyB[4], dzB[4];
    int tAA = 0, tAB = 0;
    bool tvA = true, tvB = true;

#define LOAD_OFF(KC, A0, A1, DX, DY, DZ, TA, TV)                               \
    {                                                                          \
        const int myTap_ = (KC) * 2 + (g >> 1);                                \
        TV = myTap_ < KK;                                                      \
        TA = TV ? myTap_ : 0;                                                  \
        A0 = wW3[((KC) * 2 + 0) * 64 + lane];                                  \
        A1 = wW3[((KC) * 2 + 1) * 64 + lane];                                  \
        const int lbase_ = TA * 3;                                             \
        _Pragma("unroll")                                                      \
        for (int nv = 0; nv < 4; ++nv) {                                       \
            const int wv_ = wave * 64 + nv * 16 + col;                         \
            if (TV) {                                                          \
                DX[nv] = (float)loff[wv_ * 84 + lbase_ + 0];                   \
                DY[nv] = (float)loff[wv_ * 84 + lbase_ + 1];                   \
                DZ[nv] = (float)loff[wv_ * 84 + lbase_ + 2];                   \
            } else { DX[nv] = 0.f; DY[nv] = 0.f; DZ[nv] = 0.f; }               \
        }                                                                      \
    }

#define PROC_KC(A0, A1, DX, DY, DZ, TA, TV)                                    \
    {                                                                          \
        const int rx = (TA) % 3 - 1, ry = ((TA) / 3) % 3 - 1, rz = (TA) / 9 - 1;\
        const float gyb = (float)(h + 1 + ry);                                 \
        const float gzb = (float)(d + 1 + rz);                                 \
        _Pragma("unroll")                                                      \
        for (int nv = 0; nv < 4; ++nv) {                                       \
            const int wv = wave * 64 + nv * 16 + col;                          \
            const float gx = (float)(wv + 1 + rx) + DX[nv];                    \
            const float gy = gyb + DY[nv];                                     \
            const float gz = gzb + DZ[nv];                                     \
            const float fx0f = floorf(gx), fy0f = floorf(gy), fz0f = floorf(gz);\
            const float fx = gx - fx0f, fy = gy - fy0f, fz = gz - fz0f;        \
            const int x0 = (int)fx0f - 1, y0 = (int)fy0f - 1, z0 = (int)fz0f - 1;\
            const float ifx = 1.f - fx, ify = 1.f - fy, ifz = 1.f - fz;        \
            float cw[8];                                                       \
            int cidx[8];                                                       \
            _Pragma("unroll")                                                  \
            for (int c = 0; c < 8; ++c) {                                      \
                const int cx = x0 + (c & 1);                                   \
                const int cy = y0 + ((c >> 1) & 1);                            \
                const int cz = z0 + (c >> 2);                                  \
                const bool ok = (TV) &&                                        \
                                (unsigned)cx < (unsigned)WW &&                 \
                                (unsigned)cy < (unsigned)HH &&                 \
                                (unsigned)cz < (unsigned)DD;                   \
                const float wt = ((c & 1) ? fx : ifx) *                        \
                                 (((c >> 1) & 1) ? fy : ify) *                 \
                                 ((c >> 2) ? fz : ifz);                        \
                cw[c] = ok ? wt : 0.f;                                         \
                const int cxc = min(max(cx, 0), WW - 1);                       \
                const int cyc = min(max(cy, 0), HH - 1);                       \
                const int czc = min(max(cz, 0), DD - 1);                       \
                cidx[c] = (czc * HH + cyc) * WW + cxc;                         \
            }                                                                  \
            f16x8 cv[8];                                                       \
            _Pragma("unroll")                                                  \
            for (int c = 0; c < 8; ++c)                                        \
                cv[c] = xt16[(size_t)cidx[c] * 2 + half];                      \
            union { f16x8 v; h2 s[4]; } sf;                                    \
            _Pragma("unroll")                                                  \
            for (int p = 0; p < 4; ++p) {                                      \
                sf.s[p][0] = (_Float16)0.f; sf.s[p][1] = (_Float16)0.f;        \
            }                                                                  \
            _Pragma("unroll")                                                  \
            for (int c = 0; c < 8; ++c) {                                      \
                const _Float16 wh = (_Float16)cw[c];                           \
                h2 w2; w2[0] = wh; w2[1] = wh;                                 \
                const h2* cvp = (const h2*)&cv[c];                             \
                _Pragma("unroll")                                              \
                for (int p = 0; p < 4; ++p)                                    \
                    sf.s[p] = sf.s[p] + w2 * cvp[p];                           \
            }                                                                  \
            acc3[0][nv] = __builtin_amdgcn_mfma_f32_16x16x32_f16(              \
                A0, sf.v, acc3[0][nv], 0, 0, 0);                               \
            acc3[1][nv] = __builtin_amdgcn_mfma_f32_16x16x32_f16(              \
                A1, sf.v, acc3[1][nv], 0, 0, 0);                               \
        }                                                                      \
    }

    LOAD_OFF(0, awA0, awA1, dxA, dyA, dzA, tAA, tvA)
#pragma unroll 1
    for (int kc = 0; kc < NKC; kc += 2) {
        LOAD_OFF(kc + 1, awB0, awB1, dxB, dyB, dzB, tAB, tvB)
        PROC_KC(awA0, awA1, dxA, dyA, dzA, tAA, tvA)
        if (kc + 2 < NKC)
            LOAD_OFF(kc + 2, awA0, awA1, dxA, dyA, dzA, tAA, tvA)
        PROC_KC(awB0, awB1, dxB, dyB, dzB, tAB, tvB)
    }
#undef LOAD_OFF
#undef PROC_KC

    // ---- store: D row = o-in-tile (4g+r), col = vox (16-lane contiguous) ----
    const int rowBase = (d * HH + h) * WW;
#pragma unroll
    for (int mo = 0; mo < 2; ++mo) {
#pragma unroll
        for (int r = 0; r < 4; ++r) {
            const int o = mo * 16 + 4 * g + r;
            const float b = bias[o];
#pragma unroll
            for (int nv = 0; nv < 4; ++nv) {
                const int wv = wave * 64 + nv * 16 + col;
                out[(size_t)o * DHW + rowBase + wv] = acc3[mo][nv][r] + b;
            }
        }
    }
}

// ---------------------------------------------------------------------------
// Fallback (ws too small): fully fp32, original x layout.
// ---------------------------------------------------------------------------
__global__ __launch_bounds__(128) void deform_fallback(
    const float* __restrict__ x,
    const float* __restrict__ weight,
    const float* __restrict__ bias,
    const float* __restrict__ off_w,
    const float* __restrict__ off_b,
    float* __restrict__ out)
{
    const int w = threadIdx.x;
    const int h = blockIdx.x & (HH - 1);
    const int d = blockIdx.x >> 7;

    float outacc[COUT];
#pragma unroll
    for (int o = 0; o < COUT; ++o) outacc[o] = 0.f;

    for (int k = 0; k < KK; ++k) {
        float a0 = 0.f, a1 = 0.f, a2 = 0.f;
        const float* w0 = off_w + (size_t)(k * 3 + 0) * (CIN * KK);
        const float* w1 = off_w + (size_t)(k * 3 + 1) * (CIN * KK);
        const float* w2 = off_w + (size_t)(k * 3 + 2) * (CIN * KK);
        for (int ci = 0; ci < CIN; ++ci) {
            const float* xc = x + (size_t)ci * DHW;
#pragma unroll
            for (int t = 0; t < KK; ++t) {
                const int tz = t / 9, ty = (t / 3) % 3, tx = t % 3;
                const int zz = d + tz - 1, yy = h + ty - 1, xx = w + tx - 1;
                const bool ok = (unsigned)zz < (unsigned)DD &&
                                (unsigned)yy < (unsigned)HH &&
                                (unsigned)xx < (unsigned)WW;
                const float v = ok ? xc[(zz * HH + yy) * WW + xx] : 0.f;
                a0 = fmaf(v, w0[ci * KK + t], a0);
                a1 = fmaf(v, w1[ci * KK + t], a1);
                a2 = fmaf(v, w2[ci * KK + t], a2);
            }
        }
        const float dxo = fast_tanh(a0 + off_b[k * 3 + 0]) * 4.f;
        const float dyo = fast_tanh(a1 + off_b[k * 3 + 1]) * 4.f;
        const float dzo = fast_tanh(a2 + off_b[k * 3 + 2]) * 2.f;

        const int rx = k % 3 - 1, ry = (k / 3) % 3 - 1, rz = k / 9 - 1;
        const float gx = (float)(w + 1 + rx) + dxo;
        const float gy = (float)(h + 1 + ry) + dyo;
        const float gz = (float)(d + 1 + rz) + dzo;
        const float fx0 = floorf(gx), fy0 = floorf(gy), fz0 = floorf(gz);
        const float fx = gx - fx0, fy = gy - fy0, fz = gz - fz0;
        const int x0 = (int)fx0 - 1, y0 = (int)fy0 - 1, z0 = (int)fz0 - 1;

        float samp[CIN];
#pragma unroll
        for (int ci = 0; ci < CIN; ++ci) samp[ci] = 0.f;
#pragma unroll
        for (int c = 0; c < 8; ++c) {
            const int cx = x0 + (c & 1);
            const int cy = y0 + ((c >> 1) & 1);
            const int cz = z0 + (c >> 2);
            const float wt = ((c & 1) ? fx : 1.f - fx) *
                             (((c >> 1) & 1) ? fy : 1.f - fy) *
                             ((c >> 2) ? fz : 1.f - fz);
            if ((unsigned)cx < (unsigned)WW && (unsigned)cy < (unsigned)HH &&
                (unsigned)cz < (unsigned)DD) {
                const float* p = x + ((cz * HH) + cy) * WW + cx;
#pragma unroll
                for (int ci = 0; ci < 16; ++ci)
                    samp[ci] = fmaf(wt, p[(size_t)ci * DHW], samp[ci]);
            }
        }
#pragma unroll
        for (int o = 0; o < COUT; ++o) {
            float s = 0.f;
#pragma unroll
            for (int ci = 0; ci < 16; ++ci)
                s = fmaf(weight[(o * CIN + ci) * KK + k], samp[ci], s);
            outacc[o] += s;
        }
    }
    const int vox = (d * HH + h) * WW + w;
#pragma unroll
    for (int o = 0; o < COUT; ++o)
        out[(size_t)o * DHW + vox] = outacc[o] + bias[o];
}

extern "C" void kernel_launch(void* const* d_in, const int* in_sizes, int n_in,
                              void* d_out, int out_size, void* d_ws, size_t ws_size,
                              hipStream_t stream) {
    const float* x      = (const float*)d_in[0];
    const float* weight = (const float*)d_in[1];
    const float* bias   = (const float*)d_in[2];
    const float* off_w  = (const float*)d_in[3];
    const float* off_b  = (const float*)d_in[4];
    float* out = (float*)d_out;

    if (ws_size >= WS_NEED) {
        H16* xt = (H16*)d_ws;
        _Float16* wBf = (_Float16*)((char*)d_ws + WBF_OFF);
        _Float16* wW3 = (_Float16*)((char*)d_ws + WW3_OFF);
        pack_w<<<(WBF_ELEMS + 255) / 256, 256, 0, stream>>>(off_w, weight, wBf, wW3);
        transpose_x_h<<<(DHW + 255) / 256, 256, 0, stream>>>(x, xt);
        deform_full<<<DD * HH, 128, 0, stream>>>((const f16x8*)xt, (const f16x8*)wBf,
                                                 (const f16x8*)wW3, off_b, bias, out);
    } else {
        deform_fallback<<<DD * HH, 128, 0, stream>>>(x, weight, bias, off_w, off_b, out);
    }
}